// Round 18
// baseline (530.461 us; speedup 1.0000x reference)
//
#include <hip/hip_runtime.h>

typedef unsigned short u16;
typedef unsigned int u32;
typedef float f32x4 __attribute__((ext_vector_type(4)));
typedef __bf16 bf16x8 __attribute__((ext_vector_type(8)));

// ---------- helpers ----------
__device__ __forceinline__ u16 f2bf(float f) {
  u32 u = __float_as_uint(f);
  u += 0x7fffu + ((u >> 16) & 1u);
  return (u16)(u >> 16);
}

__device__ __forceinline__ float bf2f(u16 v) {
  return __uint_as_float((u32)v << 16);
}

__device__ __forceinline__ void gload16(const u16* g, u16* l) {
  __builtin_amdgcn_global_load_lds(
      (__attribute__((address_space(1))) void*)(u16*)g,
      (__attribute__((address_space(3))) void*)l, 16, 0, 0);
}

// ---------- fused prologue: all weight packs + edge-bias cvt, one launch ----------
__device__ __forceinline__ void packw(const float* __restrict__ in,
                                      u16* __restrict__ o, int N, int K, int i) {
  const int ng = K >> 3;
  const int n = i / ng;
  const int k = (i - n * ng) * 8;
  const float4 f0 = reinterpret_cast<const float4*>(in + (size_t)n * K + k)[0];
  const float4 f1 = reinterpret_cast<const float4*>(in + (size_t)n * K + k)[1];
  u32 p0 = (u32)f2bf(f0.x) | ((u32)f2bf(f0.y) << 16);
  u32 p1 = (u32)f2bf(f0.z) | ((u32)f2bf(f0.w) << 16);
  u32 p2 = (u32)f2bf(f1.x) | ((u32)f2bf(f1.y) << 16);
  u32 p3 = (u32)f2bf(f1.z) | ((u32)f2bf(f1.w) << 16);
  u16* dst = o + ((size_t)(k >> 5) * N + n) * 32 + (k & 31);
  reinterpret_cast<uint4*>(dst)[0] = make_uint4(p0, p1, p2, p3);
}

__global__ __launch_bounds__(256) void cvt_all(
    const float* __restrict__ qkvw, const float* __restrict__ projw,
    const float* __restrict__ fc1w, const float* __restrict__ fc2w,
    const float* __restrict__ ebias, u16* __restrict__ wq, u16* __restrict__ wp,
    u16* __restrict__ wf1, u16* __restrict__ wf2, u16* __restrict__ ebb) {
  int id = blockIdx.x * 256 + threadIdx.x;
  if (id < 786432) {  // edge bias: 786432 float4 -> bf16x4
    float4 f = reinterpret_cast<const float4*>(ebias)[id];
    u32 lo = (u32)f2bf(f.x) | ((u32)f2bf(f.y) << 16);
    u32 hi = (u32)f2bf(f.z) | ((u32)f2bf(f.w) << 16);
    reinterpret_cast<uint2*>(ebb)[id] = make_uint2(lo, hi);
    return;
  }
  id -= 786432;
  if (id < 221184) { packw(qkvw, wq, 2304, 768, id); return; }
  id -= 221184;
  if (id < 73728) { packw(projw, wp, 768, 768, id); return; }
  id -= 73728;
  if (id < 294912) { packw(fc1w, wf1, 3072, 768, id); return; }
  id -= 294912;
  if (id < 294912) packw(fc2w, wf2, 768, 3072, id);
}

// ---------- LayerNorm (row of 768) -> bf16 K-tile-packed [24][M][32] ----------
__global__ __launch_bounds__(192) void ln_bf16(const float* __restrict__ x,
                                               const float* __restrict__ g,
                                               const float* __restrict__ b,
                                               u16* __restrict__ o) {
  const int row = blockIdx.x;
  const int t = threadIdx.x;  // 0..191
  const float4 a = reinterpret_cast<const float4*>(x + (size_t)row * 768)[t];
  float s = a.x + a.y + a.z + a.w;
  float ss = a.x * a.x + a.y * a.y + a.z * a.z + a.w * a.w;
#pragma unroll
  for (int m = 1; m < 64; m <<= 1) {
    s += __shfl_xor(s, m);
    ss += __shfl_xor(ss, m);
  }
  __shared__ float sb[6];
  if ((t & 63) == 0) { sb[t >> 6] = s; sb[3 + (t >> 6)] = ss; }
  __syncthreads();
  s = sb[0] + sb[1] + sb[2];
  ss = sb[3] + sb[4] + sb[5];
  const float mu = s * (1.0f / 768.0f);
  const float var = ss * (1.0f / 768.0f) - mu * mu;
  const float rs = rsqrtf(var + 1e-5f);
  const int col = t * 4;
  const float4 gv = reinterpret_cast<const float4*>(g)[t];
  const float4 bv = reinterpret_cast<const float4*>(b)[t];
  u32 lo = (u32)f2bf((a.x - mu) * rs * gv.x + bv.x) |
           ((u32)f2bf((a.y - mu) * rs * gv.y + bv.y) << 16);
  u32 hi = (u32)f2bf((a.z - mu) * rs * gv.z + bv.z) |
           ((u32)f2bf((a.w - mu) * rs * gv.w + bv.w) << 16);
  *reinterpret_cast<uint2*>(
      &o[((size_t)(col >> 5) * 16384 + row) * 32 + (col & 31)]) =
      make_uint2(lo, hi);
}

// ---------- GEMM BMIx256, 8-wave, 4-phase/K-tile schedule ----------
// Templated on BMI in {256,128}. BMI=256 path identical to the measured-best
// R15 kernel. BMI=128 (for N=768 GEMMs) doubles grid size to fill all CUs:
// wave grid stays 2Mx4N (per-wave 64x64, acc[4][4]); A slab = 1 gload;
// steady counted wait = vmcnt(3) (newest A(1)+B(2) in flight).
enum { EPI_QKV = 0, EPI_PROJ = 1, EPI_GELU = 2, EPI_OUT = 3 };

template <int EPI, int BMI>
__global__ __launch_bounds__(512, 2) void gemm_bt(
    const u16* __restrict__ A, const u16* __restrict__ W,
    const float* __restrict__ bias, const float* __restrict__ res,
    float* __restrict__ outf, u16* __restrict__ outb,
    u16* __restrict__ outq, u16* __restrict__ outk, u16* __restrict__ outv,
    int M, int N, int K) {
  constexpr int MT = BMI / 32;   // acc M-tiles per wave (8 or 4)
  constexpr int MH = MT / 2;     // frags per M-half (4 or 2)
  __shared__ u16 SA[2 * BMI * 64];
  __shared__ u16 SB[2 * 16384];
  const int tid = threadIdx.x;
  const int wid = tid >> 6, l = tid & 63;
  const int wm = wid >> 2, wn = wid & 3;
  const int lg = l >> 4, lc = l & 15;

  // bijective XCD-chunked swizzle (nwg % 8 == 0 for all launches here)
  const u32 nbn = gridDim.x;
  const u32 orig = blockIdx.y * nbn + blockIdx.x;
  const u32 cpx = (nbn * gridDim.y) >> 3;
  const u32 wgid = (orig & 7) * cpx + (orig >> 3);
  const int bn = wgid % nbn;
  const int bm = wgid / nbn;

  const size_t Msl = (size_t)M * 32;
  const size_t Nsl = (size_t)N * 32;
  const size_t lane_a = (size_t)(bm * BMI + wid * 16 + (l >> 2)) * 32 +
                        (((l & 3) ^ ((l >> 3) & 3)) << 3);
  const size_t lane_w = (size_t)(bn * 256 + wid * 16 + (l >> 2)) * 32 +
                        (((l & 3) ^ ((l >> 3) & 3)) << 3);
  // fragment-read swizzled granule (u16 units): lg ^ ((lc>>1)&3)
  const int sg = (lg ^ ((lc >> 1) & 3)) << 3;

  f32x4 acc[MT][4] = {};

  const int NT = K >> 6;  // K-tiles of 64

// stage A slab (BMI rows x 32k) of K-tile T1, k-slab s, into buf n
#define STAGE_A(T1, s, n)                                               \
  {                                                                     \
    const u16* Au_ = A + (size_t)(2 * (T1) + (s)) * Msl + lane_a;       \
    gload16(Au_, &SA[(n) * (BMI * 64) + (s) * (BMI * 32) + wid * 512]); \
    if constexpr (BMI == 256)                                           \
      gload16(Au_ + 4096,                                               \
              &SA[(n) * (BMI * 64) + (s) * (BMI * 32) + 4096 + wid * 512]); \
  }
#define STAGE_B(T1, s, n)                                               \
  {                                                                     \
    const u16* Wu_ = W + (size_t)(2 * (T1) + (s)) * Nsl + lane_w;       \
    gload16(Wu_, &SB[(n) * 16384 + (s) * 8192 + wid * 512]);            \
    gload16(Wu_ + 4096, &SB[(n) * 16384 + (s) * 8192 + 4096 + wid * 512]); \
  }
#define RDA(c, ks, mh)                                                  \
  {                                                                     \
    _Pragma("unroll") for (int mi = 0; mi < MH; ++mi) afq[mi] =         \
        *reinterpret_cast<const bf16x8*>(                               \
            &SA[(c) * (BMI * 64) + (ks) * (BMI * 32) +                  \
                (wm * (BMI / 2) + ((mh) * MH + mi) * 16 + lc) * 32 + sg]); \
  }
#define RDB(c, ks, dst)                                                 \
  {                                                                     \
    _Pragma("unroll") for (int ni = 0; ni < 4; ++ni) dst[ni] =          \
        *reinterpret_cast<const bf16x8*>(                               \
            &SB[(c) * 16384 + (ks) * 8192 +                             \
                (wn * 64 + ni * 16 + lc) * 32 + sg]);                   \
  }
#define MM(mh, BK)                                                      \
  {                                                                     \
    __builtin_amdgcn_s_setprio(1);                                      \
    _Pragma("unroll") for (int mi = 0; mi < MH; ++mi)                   \
        _Pragma("unroll") for (int ni = 0; ni < 4; ++ni)                \
            acc[(mh) * MH + mi][ni] =                                   \
                __builtin_amdgcn_mfma_f32_16x16x32_bf16(                \
                    afq[mi], BK[ni], acc[(mh) * MH + mi][ni], 0, 0, 0); \
    __builtin_amdgcn_s_setprio(0);                                      \
  }
#define VMCNT_STEADY                                                    \
  if constexpr (BMI == 256) {                                           \
    asm volatile("s_waitcnt vmcnt(4)" ::: "memory");                    \
  } else {                                                              \
    asm volatile("s_waitcnt vmcnt(3)" ::: "memory");                    \
  }
#define LGKM0 asm volatile("s_waitcnt lgkmcnt(0)" ::: "memory")
#define BAR __builtin_amdgcn_s_barrier()

  // prologue: K-tile 0 fully staged into buffer 0
  STAGE_A(0, 0, 0);
  STAGE_A(0, 1, 0);
  STAGE_B(0, 0, 0);
  STAGE_B(0, 1, 0);
  asm volatile("s_waitcnt vmcnt(0)" ::: "memory");
  BAR;

  for (int T = 0; T < NT; ++T) {
    const int c = T & 1, n = c ^ 1;
    const bool st = (T + 1 < NT);
    bf16x8 afq[MH], bk0[4], bk1[4];
    // ---- P1: ks0 x Mhalf0 (ds_read | stage A-s0) ----
    RDA(c, 0, 0);
    RDB(c, 0, bk0);
    if (st) STAGE_A(T + 1, 0, n);
    BAR;
    LGKM0;
    MM(0, bk0);
    BAR;
    // ---- P2: ks0 x Mhalf1 (ds_read | stage B-s0) ----
    RDA(c, 0, 1);
    if (st) STAGE_B(T + 1, 0, n);
    BAR;
    LGKM0;
    MM(1, bk0);
    // counted: confirms prev tile's A-s1+B-s1 (oldest), needed by P3
    if (st) {
      VMCNT_STEADY;
    } else {
      asm volatile("s_waitcnt vmcnt(0)" ::: "memory");
    }
    BAR;
    // ---- P3: ks1 x Mhalf0 (ds_read | stage A-s1) ----
    RDA(c, 1, 0);
    RDB(c, 1, bk1);
    if (st) STAGE_A(T + 1, 1, n);
    BAR;
    LGKM0;
    MM(0, bk1);
    BAR;
    // ---- P4: ks1 x Mhalf1 (ds_read | stage B-s1) ----
    RDA(c, 1, 1);
    if (st) STAGE_B(T + 1, 1, n);
    BAR;
    LGKM0;
    MM(1, bk1);
    // counted: confirms next tile's A-s0+B-s0 (oldest), needed by its P1
    if (st) VMCNT_STEADY;
    BAR;
  }
#undef STAGE_A
#undef STAGE_B
#undef RDA
#undef RDB
#undef MM
#undef VMCNT_STEADY
#undef LGKM0
#undef BAR

  const int rbase = bm * BMI + wm * (BMI / 2);
  const int cbase = bn * 256 + wn * 64;
#pragma unroll
  for (int mi = 0; mi < MT; ++mi) {
#pragma unroll
    for (int ni = 0; ni < 4; ++ni) {
#pragma unroll
      for (int r = 0; r < 4; ++r) {
        const int i = rbase + mi * 16 + lg * 4 + r;
        const int j = cbase + ni * 16 + lc;
        float v = acc[mi][ni][r] + bias[j];
        if constexpr (EPI == EPI_QKV) {
          const int t = j / 768;
          const int rr = j - t * 768;
          const int h = rr >> 6, hd = rr & 63;
          const int bb = i >> 9, ssi = i & 511;
          if (t == 0) {
            outq[((size_t)(bb * 12 + h) * 512 + ssi) * 64 + hd] = f2bf(v * 0.125f);
          } else if (t == 1) {
            outk[((size_t)(bb * 12 + h) * 512 + ssi) * 64 + hd] = f2bf(v);
          } else {
            // V stored pre-transposed: [bh][d][tok]
            outv[((size_t)(bb * 12 + h) * 64 + hd) * 512 + ssi] = f2bf(v);
          }
        } else if constexpr (EPI == EPI_PROJ) {
          outf[(size_t)i * 768 + j] = v + res[(size_t)i * 768 + j];
        } else if constexpr (EPI == EPI_GELU) {
          // tanh-form GELU (max err ~3e-4)
          float z = -1.5957691216f * v - 0.07135481627f * v * v * v;
          float gl = v * __builtin_amdgcn_rcpf(1.0f + __expf(z));
          // K-tile-packed for fc2's A: [96][16384][32]
          outb[((size_t)(j >> 5) * 16384 + i) * 32 + (j & 31)] = f2bf(gl);
        } else {
          outf[(size_t)i * 768 + j] = v + res[(size_t)i * 768 + j];
        }
      }
    }
  }
}

// ---------- attention: LDS-staged K/V, DIRECT global bias reads, flash 4x128 ----------
// Output written K-tile-packed [24][16384][32] (proj GEMM's A operand).
__global__ __launch_bounds__(256) void attn_fwd(const u16* __restrict__ q,
                                                const u16* __restrict__ k,
                                                const u16* __restrict__ vt,
                                                const u16* __restrict__ ebb,
                                                u16* __restrict__ o) {
  __shared__ u16 Ks[128 * 64];
  __shared__ u16 Vs[64 * 128];
  __shared__ u16 P[4 * 1024];
  const int tid = threadIdx.x;
  const int w = tid >> 6, l = tid & 63;
  const int lg = l >> 4, lc = l & 15;
  const int xcd = blockIdx.x & 7;
  const int wg = xcd * 384 + (blockIdx.x >> 3);
  const int qt = wg & 7;
  const int b = (wg >> 3) & 31;
  const int h = wg >> 8;
  const int bh = b * 12 + h;
  const int q0 = qt * 64;
  const u16* qp = q + (size_t)bh * 512 * 64;
  const u16* kp = k + (size_t)bh * 512 * 64;
  const u16* vtp = vt + (size_t)bh * 64 * 512;
  const u16* bp = ebb + (size_t)h * 262144 + (size_t)(q0 + w * 16 + lg * 4) * 512 + lc;

  bf16x8 aq[2];
#pragma unroll
  for (int kk = 0; kk < 2; ++kk)
    aq[kk] = *reinterpret_cast<const bf16x8*>(qp + (q0 + w * 16 + lc) * 64 + kk * 32 + lg * 8);

  float m[4], lsum[4];
  f32x4 oa[4] = {};
#pragma unroll
  for (int r = 0; r < 4; ++r) { m[r] = -1e30f; lsum[r] = 0.f; }

  const int krow_l = l >> 3;
  const int kgr = ((l & 7) ^ (l >> 3)) << 3;
  const int vrow_l = l >> 4;
  const int vswz = 4 * (w & 1) + (l >> 4);
  const int vgr = (((l & 15) ^ vswz)) << 3;
  char* Pw = (char*)&P[w * 1024];

  for (int kc = 0; kc < 4; ++kc) {
    const int kb = kc * 128;
    __syncthreads();
#pragma unroll
    for (int i = 0; i < 4; ++i) {
      const int grp = i * 4 + w;
      gload16(kp + (size_t)(kb + grp * 8 + krow_l) * 64 + kgr, &Ks[grp * 512]);
      gload16(vtp + (size_t)(grp * 4 + vrow_l) * 512 + kb + vgr, &Vs[grp * 512]);
    }
    __syncthreads();

    f32x4 s[8] = {};
#pragma unroll
    for (int kt = 0; kt < 8; ++kt) {
      const int kbyte = (kt * 16 + lc) * 128;
      const int sw = lc & 7;
      bf16x8 b0 = *reinterpret_cast<const bf16x8*>((const char*)Ks + kbyte + ((lg ^ sw) << 4));
      bf16x8 b1 = *reinterpret_cast<const bf16x8*>((const char*)Ks + kbyte + (((4 + lg) ^ sw) << 4));
      s[kt] = __builtin_amdgcn_mfma_f32_16x16x32_bf16(aq[0], b0, s[kt], 0, 0, 0);
      s[kt] = __builtin_amdgcn_mfma_f32_16x16x32_bf16(aq[1], b1, s[kt], 0, 0, 0);
    }
    // bias: direct global reads (bf16), no reuse -> no staging
#pragma unroll
    for (int kt = 0; kt < 8; ++kt)
#pragma unroll
      for (int r = 0; r < 4; ++r)
        s[kt][r] += bf2f(bp[(size_t)r * 512 + kb + kt * 16]);
#pragma unroll
    for (int r = 0; r < 4; ++r) {
      float mc = s[0][r];
#pragma unroll
      for (int kt = 1; kt < 8; ++kt) mc = fmaxf(mc, s[kt][r]);
      mc = fmaxf(mc, __shfl_xor(mc, 1));
      mc = fmaxf(mc, __shfl_xor(mc, 2));
      mc = fmaxf(mc, __shfl_xor(mc, 4));
      mc = fmaxf(mc, __shfl_xor(mc, 8));
      const float mn = fmaxf(m[r], mc);
      const float al = __expf(m[r] - mn);
      m[r] = mn;
      float sum = 0.f;
#pragma unroll
      for (int kt = 0; kt < 8; ++kt) {
        float pv = __expf(s[kt][r] - mn);
        s[kt][r] = pv;
        sum += pv;
      }
      sum += __shfl_xor(sum, 1);
      sum += __shfl_xor(sum, 2);
      sum += __shfl_xor(sum, 4);
      sum += __shfl_xor(sum, 8);
      lsum[r] = lsum[r] * al + sum;
#pragma unroll
      for (int ni = 0; ni < 4; ++ni) oa[ni][r] *= al;
    }
#pragma unroll
    for (int kt = 0; kt < 8; ++kt)
#pragma unroll
      for (int r = 0; r < 4; ++r) {
        const int row = lg * 4 + r;
        int byte = (row << 8) + ((kt * 16 + lc) << 1);
        byte ^= (row & 7) << 4;
        *reinterpret_cast<u16*>(Pw + byte) = f2bf(s[kt][r]);
      }
#pragma unroll
    for (int ks = 0; ks < 4; ++ks) {
      int pbyte = (lc << 8) + ks * 64 + lg * 16;
      pbyte ^= (lc & 7) << 4;
      bf16x8 pa = *reinterpret_cast<const bf16x8*>(Pw + pbyte);
#pragma unroll
      for (int ni = 0; ni < 4; ++ni) {
        const int vbyte = (ni * 16 + lc) * 256 + (((ks * 4 + lg) ^ (lc & 7)) << 4);
        bf16x8 bv = *reinterpret_cast<const bf16x8*>((const char*)Vs + vbyte);
        oa[ni] = __builtin_amdgcn_mfma_f32_16x16x32_bf16(pa, bv, oa[ni], 0, 0, 0);
      }
    }
  }

  float inv[4];
#pragma unroll
  for (int r = 0; r < 4; ++r) inv[r] = 1.0f / lsum[r];
#pragma unroll
  for (int ni = 0; ni < 4; ++ni)
#pragma unroll
    for (int r = 0; r < 4; ++r) {
      const int i = b * 512 + q0 + w * 16 + lg * 4 + r;
      const int j = h * 64 + ni * 16 + lc;
      o[((size_t)(j >> 5) * 16384 + i) * 32 + (j & 31)] = f2bf(oa[ni][r] * inv[r]);
    }
}

// ---------- launch ----------
extern "C" void kernel_launch(void* const* d_in, const int* in_sizes, int n_in,
                              void* d_out, int out_size, void* d_ws, size_t ws_size,
                              hipStream_t stream) {
  const float* x     = (const float*)d_in[0];
  const float* ebias = (const float*)d_in[1];
  const float* ln1g  = (const float*)d_in[2];
  const float* ln1b  = (const float*)d_in[3];
  const float* qkvw  = (const float*)d_in[4];
  const float* qkvb  = (const float*)d_in[5];
  const float* projw = (const float*)d_in[6];
  const float* projb = (const float*)d_in[7];
  const float* ln2g  = (const float*)d_in[8];
  const float* ln2b  = (const float*)d_in[9];
  const float* fc1w  = (const float*)d_in[10];
  const float* fc1b  = (const float*)d_in[11];
  const float* fc2w  = (const float*)d_in[12];
  const float* fc2b  = (const float*)d_in[13];
  float* out = (float*)d_out;

  char* p = (char*)d_ws;
  const size_t ACT = (size_t)16384 * 768 * 2;  // 25165824 B
  u16* xnb = (u16*)(p);                        // xn packed; later attn-out packed
  u16* qb  = (u16*)(p + ACT);
  u16* kb  = (u16*)(p + 2 * ACT);              // k; later ln2-out packed
  u16* vb  = (u16*)(p + 3 * ACT);              // V^T [bh][d][tok]
  u16* ffb = (u16*)(p + 4 * ACT);              // fc1 out packed; ebb shares (time-disjoint)
  u16* ebb = (u16*)(p + 4 * ACT);              // bf16 edge bias
  float* x2 = (float*)(p + 4 * ACT + (size_t)16384 * 3072 * 2);
  char* wz = p + 4 * ACT + (size_t)16384 * 3072 * 2 + (size_t)16384 * 768 * 4;
  u16* wq  = (u16*)wz;
  u16* wp  = wq + (size_t)2304 * 768;
  u16* wf1 = wp + (size_t)768 * 768;
  u16* wf2 = wf1 + (size_t)3072 * 768;

  cvt_all<<<6528, 256, 0, stream>>>(qkvw, projw, fc1w, fc2w, ebias,
                                    wq, wp, wf1, wf2, ebb);

  ln_bf16<<<16384, 192, 0, stream>>>(x, ln1g, ln1b, xnb);

  gemm_bt<EPI_QKV, 256><<<dim3(9, 64), 512, 0, stream>>>(
      xnb, wq, qkvb, nullptr, nullptr, nullptr, qb, kb, vb, 16384, 2304, 768);

  attn_fwd<<<3072, 256, 0, stream>>>(qb, kb, vb, ebb, xnb);

  gemm_bt<EPI_PROJ, 128><<<dim3(3, 128), 512, 0, stream>>>(
      xnb, wp, projb, x, x2, nullptr, nullptr, nullptr, nullptr, 16384, 768, 768);

  ln_bf16<<<16384, 192, 0, stream>>>(x2, ln2g, ln2b, kb);

  gemm_bt<EPI_GELU, 256><<<dim3(12, 64), 512, 0, stream>>>(
      kb, wf1, fc1b, nullptr, nullptr, ffb, nullptr, nullptr, nullptr, 16384, 3072, 768);

  gemm_bt<EPI_OUT, 128><<<dim3(3, 128), 512, 0, stream>>>(
      ffb, wf2, fc2b, x2, out, nullptr, nullptr, nullptr, nullptr, 16384, 768, 3072);
}

// Round 19
// 496.665 us; speedup vs baseline: 1.0680x; 1.0680x over previous
//
#include <hip/hip_runtime.h>

typedef unsigned short u16;
typedef unsigned int u32;
typedef float f32x4 __attribute__((ext_vector_type(4)));
typedef __bf16 bf16x8 __attribute__((ext_vector_type(8)));

// ---------- helpers ----------
__device__ __forceinline__ u16 f2bf(float f) {
  u32 u = __float_as_uint(f);
  u += 0x7fffu + ((u >> 16) & 1u);
  return (u16)(u >> 16);
}

__device__ __forceinline__ float bf2f(u16 v) {
  return __uint_as_float((u32)v << 16);
}

__device__ __forceinline__ void gload16(const u16* g, u16* l) {
  __builtin_amdgcn_global_load_lds(
      (__attribute__((address_space(1))) void*)(u16*)g,
      (__attribute__((address_space(3))) void*)l, 16, 0, 0);
}

// ---------- fused prologue: all weight packs + edge-bias cvt, one launch ----------
__device__ __forceinline__ void packw(const float* __restrict__ in,
                                      u16* __restrict__ o, int N, int K, int i) {
  const int ng = K >> 3;
  const int n = i / ng;
  const int k = (i - n * ng) * 8;
  const float4 f0 = reinterpret_cast<const float4*>(in + (size_t)n * K + k)[0];
  const float4 f1 = reinterpret_cast<const float4*>(in + (size_t)n * K + k)[1];
  u32 p0 = (u32)f2bf(f0.x) | ((u32)f2bf(f0.y) << 16);
  u32 p1 = (u32)f2bf(f0.z) | ((u32)f2bf(f0.w) << 16);
  u32 p2 = (u32)f2bf(f1.x) | ((u32)f2bf(f1.y) << 16);
  u32 p3 = (u32)f2bf(f1.z) | ((u32)f2bf(f1.w) << 16);
  u16* dst = o + ((size_t)(k >> 5) * N + n) * 32 + (k & 31);
  reinterpret_cast<uint4*>(dst)[0] = make_uint4(p0, p1, p2, p3);
}

__global__ __launch_bounds__(256) void cvt_all(
    const float* __restrict__ qkvw, const float* __restrict__ projw,
    const float* __restrict__ fc1w, const float* __restrict__ fc2w,
    const float* __restrict__ ebias, u16* __restrict__ wq, u16* __restrict__ wp,
    u16* __restrict__ wf1, u16* __restrict__ wf2, u16* __restrict__ ebb) {
  int id = blockIdx.x * 256 + threadIdx.x;
  if (id < 786432) {  // edge bias: 786432 float4 -> bf16x4
    float4 f = reinterpret_cast<const float4*>(ebias)[id];
    u32 lo = (u32)f2bf(f.x) | ((u32)f2bf(f.y) << 16);
    u32 hi = (u32)f2bf(f.z) | ((u32)f2bf(f.w) << 16);
    reinterpret_cast<uint2*>(ebb)[id] = make_uint2(lo, hi);
    return;
  }
  id -= 786432;
  if (id < 221184) { packw(qkvw, wq, 2304, 768, id); return; }
  id -= 221184;
  if (id < 73728) { packw(projw, wp, 768, 768, id); return; }
  id -= 73728;
  if (id < 294912) { packw(fc1w, wf1, 3072, 768, id); return; }
  id -= 294912;
  if (id < 294912) packw(fc2w, wf2, 768, 3072, id);
}

// ---------- LayerNorm (row of 768) -> bf16 K-tile-packed [24][M][32] ----------
__global__ __launch_bounds__(192) void ln_bf16(const float* __restrict__ x,
                                               const float* __restrict__ g,
                                               const float* __restrict__ b,
                                               u16* __restrict__ o) {
  const int row = blockIdx.x;
  const int t = threadIdx.x;  // 0..191
  const float4 a = reinterpret_cast<const float4*>(x + (size_t)row * 768)[t];
  float s = a.x + a.y + a.z + a.w;
  float ss = a.x * a.x + a.y * a.y + a.z * a.z + a.w * a.w;
#pragma unroll
  for (int m = 1; m < 64; m <<= 1) {
    s += __shfl_xor(s, m);
    ss += __shfl_xor(ss, m);
  }
  __shared__ float sb[6];
  if ((t & 63) == 0) { sb[t >> 6] = s; sb[3 + (t >> 6)] = ss; }
  __syncthreads();
  s = sb[0] + sb[1] + sb[2];
  ss = sb[3] + sb[4] + sb[5];
  const float mu = s * (1.0f / 768.0f);
  const float var = ss * (1.0f / 768.0f) - mu * mu;
  const float rs = rsqrtf(var + 1e-5f);
  const int col = t * 4;
  const float4 gv = reinterpret_cast<const float4*>(g)[t];
  const float4 bv = reinterpret_cast<const float4*>(b)[t];
  u32 lo = (u32)f2bf((a.x - mu) * rs * gv.x + bv.x) |
           ((u32)f2bf((a.y - mu) * rs * gv.y + bv.y) << 16);
  u32 hi = (u32)f2bf((a.z - mu) * rs * gv.z + bv.z) |
           ((u32)f2bf((a.w - mu) * rs * gv.w + bv.w) << 16);
  *reinterpret_cast<uint2*>(
      &o[((size_t)(col >> 5) * 16384 + row) * 32 + (col & 31)]) =
      make_uint2(lo, hi);
}

// ---------- GEMM 256x256, 8-wave, m201-faithful 4-phase/K-tile schedule ----------
// BK=64 K-tile, 2-buffer LDS dbuf. Phase = (kslab, Mhalf): {4-8 ds_read |
// 2 gload stage | BAR | lgkmcnt(0) | setprio 16 MFMA | BAR}. Counted
// vmcnt(4) at phase-2/phase-4 ends (never 0 mid-loop) — T3+T4 discipline.
enum { EPI_QKV = 0, EPI_PROJ = 1, EPI_GELU = 2, EPI_OUT = 3 };

template <int EPI>
__global__ __launch_bounds__(512, 2) void gemm_bt(
    const u16* __restrict__ A, const u16* __restrict__ W,
    const float* __restrict__ bias, const float* __restrict__ res,
    float* __restrict__ outf, u16* __restrict__ outb,
    u16* __restrict__ outq, u16* __restrict__ outk, u16* __restrict__ outv,
    int M, int N, int K) {
  __shared__ u16 SA[2 * 16384];
  __shared__ u16 SB[2 * 16384];
  const int tid = threadIdx.x;
  const int wid = tid >> 6, l = tid & 63;
  const int wm = wid >> 2, wn = wid & 3;
  const int lg = l >> 4, lc = l & 15;

  // bijective XCD-chunked swizzle (nwg % 8 == 0 for all launches here)
  const u32 nbn = gridDim.x;
  const u32 orig = blockIdx.y * nbn + blockIdx.x;
  const u32 cpx = (nbn * gridDim.y) >> 3;
  const u32 wgid = (orig & 7) * cpx + (orig >> 3);
  const int bn = wgid % nbn;
  const int bm = wgid / nbn;

  const size_t Msl = (size_t)M * 32;
  const size_t Nsl = (size_t)N * 32;
  const size_t lane_a = (size_t)(bm * 256 + wid * 16 + (l >> 2)) * 32 +
                        (((l & 3) ^ ((l >> 3) & 3)) << 3);
  const size_t lane_w = (size_t)(bn * 256 + wid * 16 + (l >> 2)) * 32 +
                        (((l & 3) ^ ((l >> 3) & 3)) << 3);
  // fragment-read swizzled granule (u16 units): lg ^ ((lc>>1)&3)
  const int sg = (lg ^ ((lc >> 1) & 3)) << 3;

  f32x4 acc[8][4] = {};

  const int NT = K >> 6;  // 12 or 48 K-tiles of 64

// stage one operand slab (256 rows x 32k) of K-tile T1, k-slab s, into buf n
#define STAGE_A(T1, s, n)                                               \
  {                                                                     \
    const u16* Au_ = A + (size_t)(2 * (T1) + (s)) * Msl + lane_a;       \
    gload16(Au_, &SA[(n) * 16384 + (s) * 8192 + wid * 512]);            \
    gload16(Au_ + 4096, &SA[(n) * 16384 + (s) * 8192 + 4096 + wid * 512]); \
  }
#define STAGE_B(T1, s, n)                                               \
  {                                                                     \
    const u16* Wu_ = W + (size_t)(2 * (T1) + (s)) * Nsl + lane_w;       \
    gload16(Wu_, &SB[(n) * 16384 + (s) * 8192 + wid * 512]);            \
    gload16(Wu_ + 4096, &SB[(n) * 16384 + (s) * 8192 + 4096 + wid * 512]); \
  }
#define RDA(c, ks, mh)                                                  \
  {                                                                     \
    _Pragma("unroll") for (int mi = 0; mi < 4; ++mi) afq[mi] =          \
        *reinterpret_cast<const bf16x8*>(                               \
            &SA[(c) * 16384 + (ks) * 8192 +                             \
                (wm * 128 + ((mh) * 4 + mi) * 16 + lc) * 32 + sg]);     \
  }
#define RDB(c, ks, dst)                                                 \
  {                                                                     \
    _Pragma("unroll") for (int ni = 0; ni < 4; ++ni) dst[ni] =          \
        *reinterpret_cast<const bf16x8*>(                               \
            &SB[(c) * 16384 + (ks) * 8192 +                             \
                (wn * 64 + ni * 16 + lc) * 32 + sg]);                   \
  }
#define MM(mh, BK)                                                      \
  {                                                                     \
    __builtin_amdgcn_s_setprio(1);                                      \
    _Pragma("unroll") for (int mi = 0; mi < 4; ++mi)                    \
        _Pragma("unroll") for (int ni = 0; ni < 4; ++ni)                \
            acc[(mh) * 4 + mi][ni] =                                    \
                __builtin_amdgcn_mfma_f32_16x16x32_bf16(                \
                    afq[mi], BK[ni], acc[(mh) * 4 + mi][ni], 0, 0, 0);  \
    __builtin_amdgcn_s_setprio(0);                                      \
  }
#define LGKM0 asm volatile("s_waitcnt lgkmcnt(0)" ::: "memory")
#define BAR __builtin_amdgcn_s_barrier()

  // prologue: K-tile 0 fully staged into buffer 0
  STAGE_A(0, 0, 0);
  STAGE_A(0, 1, 0);
  STAGE_B(0, 0, 0);
  STAGE_B(0, 1, 0);
  asm volatile("s_waitcnt vmcnt(0)" ::: "memory");
  BAR;

  for (int T = 0; T < NT; ++T) {
    const int c = T & 1, n = c ^ 1;
    const bool st = (T + 1 < NT);
    bf16x8 afq[4], bk0[4], bk1[4];
    // ---- P1: ks0 x Mhalf0 (8 ds_read | stage A-s0) ----
    RDA(c, 0, 0);
    RDB(c, 0, bk0);
    if (st) STAGE_A(T + 1, 0, n);
    BAR;
    LGKM0;
    MM(0, bk0);
    BAR;
    // ---- P2: ks0 x Mhalf1 (4 ds_read | stage B-s0) ----
    RDA(c, 0, 1);
    if (st) STAGE_B(T + 1, 0, n);
    BAR;
    LGKM0;
    MM(1, bk0);
    // counted: confirms prev tile's A-s1+B-s1 (oldest 4), needed by P3
    if (st) {
      asm volatile("s_waitcnt vmcnt(4)" ::: "memory");
    } else {
      asm volatile("s_waitcnt vmcnt(0)" ::: "memory");
    }
    BAR;
    // ---- P3: ks1 x Mhalf0 (8 ds_read | stage A-s1) ----
    RDA(c, 1, 0);
    RDB(c, 1, bk1);
    if (st) STAGE_A(T + 1, 1, n);
    BAR;
    LGKM0;
    MM(0, bk1);
    BAR;
    // ---- P4: ks1 x Mhalf1 (4 ds_read | stage B-s1) ----
    RDA(c, 1, 1);
    if (st) STAGE_B(T + 1, 1, n);
    BAR;
    LGKM0;
    MM(1, bk1);
    // counted: confirms next tile's A-s0+B-s0 (oldest 4), needed by its P1
    if (st) asm volatile("s_waitcnt vmcnt(4)" ::: "memory");
    BAR;
  }
#undef STAGE_A
#undef STAGE_B
#undef RDA
#undef RDB
#undef MM
#undef LGKM0
#undef BAR

  const int rbase = bm * 256 + wm * 128;
  const int cbase = bn * 256 + wn * 64;
#pragma unroll
  for (int mi = 0; mi < 8; ++mi) {
#pragma unroll
    for (int ni = 0; ni < 4; ++ni) {
#pragma unroll
      for (int r = 0; r < 4; ++r) {
        const int i = rbase + mi * 16 + lg * 4 + r;
        const int j = cbase + ni * 16 + lc;
        float v = acc[mi][ni][r] + bias[j];
        if constexpr (EPI == EPI_QKV) {
          const int t = j / 768;
          const int rr = j - t * 768;
          const int h = rr >> 6, hd = rr & 63;
          const int bb = i >> 9, ssi = i & 511;
          if (t == 0) {
            outq[((size_t)(bb * 12 + h) * 512 + ssi) * 64 + hd] = f2bf(v * 0.125f);
          } else if (t == 1) {
            outk[((size_t)(bb * 12 + h) * 512 + ssi) * 64 + hd] = f2bf(v);
          } else {
            // V stored pre-transposed: [bh][d][tok]
            outv[((size_t)(bb * 12 + h) * 64 + hd) * 512 + ssi] = f2bf(v);
          }
        } else if constexpr (EPI == EPI_PROJ) {
          outf[(size_t)i * 768 + j] = v + res[(size_t)i * 768 + j];
        } else if constexpr (EPI == EPI_GELU) {
          // tanh-form GELU (max err ~3e-4)
          float z = -1.5957691216f * v - 0.07135481627f * v * v * v;
          float gl = v * __builtin_amdgcn_rcpf(1.0f + __expf(z));
          // K-tile-packed for fc2's A: [96][16384][32]
          outb[((size_t)(j >> 5) * 16384 + i) * 32 + (j & 31)] = f2bf(gl);
        } else {
          outf[(size_t)i * 768 + j] = v + res[(size_t)i * 768 + j];
        }
      }
    }
  }
}

// ---------- attention: LDS-staged K/V, DIRECT global bias reads, flash 4x128 ----------
// Output written K-tile-packed [24][16384][32] (proj GEMM's A operand).
__global__ __launch_bounds__(256) void attn_fwd(const u16* __restrict__ q,
                                                const u16* __restrict__ k,
                                                const u16* __restrict__ vt,
                                                const u16* __restrict__ ebb,
                                                u16* __restrict__ o) {
  __shared__ u16 Ks[128 * 64];
  __shared__ u16 Vs[64 * 128];
  __shared__ u16 P[4 * 1024];
  const int tid = threadIdx.x;
  const int w = tid >> 6, l = tid & 63;
  const int lg = l >> 4, lc = l & 15;
  const int xcd = blockIdx.x & 7;
  const int wg = xcd * 384 + (blockIdx.x >> 3);
  const int qt = wg & 7;
  const int b = (wg >> 3) & 31;
  const int h = wg >> 8;
  const int bh = b * 12 + h;
  const int q0 = qt * 64;
  const u16* qp = q + (size_t)bh * 512 * 64;
  const u16* kp = k + (size_t)bh * 512 * 64;
  const u16* vtp = vt + (size_t)bh * 64 * 512;
  const u16* bp = ebb + (size_t)h * 262144 + (size_t)(q0 + w * 16 + lg * 4) * 512 + lc;

  bf16x8 aq[2];
#pragma unroll
  for (int kk = 0; kk < 2; ++kk)
    aq[kk] = *reinterpret_cast<const bf16x8*>(qp + (q0 + w * 16 + lc) * 64 + kk * 32 + lg * 8);

  float m[4], lsum[4];
  f32x4 oa[4] = {};
#pragma unroll
  for (int r = 0; r < 4; ++r) { m[r] = -1e30f; lsum[r] = 0.f; }

  const int krow_l = l >> 3;
  const int kgr = ((l & 7) ^ (l >> 3)) << 3;
  const int vrow_l = l >> 4;
  const int vswz = 4 * (w & 1) + (l >> 4);
  const int vgr = (((l & 15) ^ vswz)) << 3;
  char* Pw = (char*)&P[w * 1024];

  for (int kc = 0; kc < 4; ++kc) {
    const int kb = kc * 128;
    __syncthreads();
#pragma unroll
    for (int i = 0; i < 4; ++i) {
      const int grp = i * 4 + w;
      gload16(kp + (size_t)(kb + grp * 8 + krow_l) * 64 + kgr, &Ks[grp * 512]);
      gload16(vtp + (size_t)(grp * 4 + vrow_l) * 512 + kb + vgr, &Vs[grp * 512]);
    }
    __syncthreads();

    f32x4 s[8] = {};
#pragma unroll
    for (int kt = 0; kt < 8; ++kt) {
      const int kbyte = (kt * 16 + lc) * 128;
      const int sw = lc & 7;
      bf16x8 b0 = *reinterpret_cast<const bf16x8*>((const char*)Ks + kbyte + ((lg ^ sw) << 4));
      bf16x8 b1 = *reinterpret_cast<const bf16x8*>((const char*)Ks + kbyte + (((4 + lg) ^ sw) << 4));
      s[kt] = __builtin_amdgcn_mfma_f32_16x16x32_bf16(aq[0], b0, s[kt], 0, 0, 0);
      s[kt] = __builtin_amdgcn_mfma_f32_16x16x32_bf16(aq[1], b1, s[kt], 0, 0, 0);
    }
    // bias: direct global reads (bf16), no reuse -> no staging
#pragma unroll
    for (int kt = 0; kt < 8; ++kt)
#pragma unroll
      for (int r = 0; r < 4; ++r)
        s[kt][r] += bf2f(bp[(size_t)r * 512 + kb + kt * 16]);
#pragma unroll
    for (int r = 0; r < 4; ++r) {
      float mc = s[0][r];
#pragma unroll
      for (int kt = 1; kt < 8; ++kt) mc = fmaxf(mc, s[kt][r]);
      mc = fmaxf(mc, __shfl_xor(mc, 1));
      mc = fmaxf(mc, __shfl_xor(mc, 2));
      mc = fmaxf(mc, __shfl_xor(mc, 4));
      mc = fmaxf(mc, __shfl_xor(mc, 8));
      const float mn = fmaxf(m[r], mc);
      const float al = __expf(m[r] - mn);
      m[r] = mn;
      float sum = 0.f;
#pragma unroll
      for (int kt = 0; kt < 8; ++kt) {
        float pv = __expf(s[kt][r] - mn);
        s[kt][r] = pv;
        sum += pv;
      }
      sum += __shfl_xor(sum, 1);
      sum += __shfl_xor(sum, 2);
      sum += __shfl_xor(sum, 4);
      sum += __shfl_xor(sum, 8);
      lsum[r] = lsum[r] * al + sum;
#pragma unroll
      for (int ni = 0; ni < 4; ++ni) oa[ni][r] *= al;
    }
#pragma unroll
    for (int kt = 0; kt < 8; ++kt)
#pragma unroll
      for (int r = 0; r < 4; ++r) {
        const int row = lg * 4 + r;
        int byte = (row << 8) + ((kt * 16 + lc) << 1);
        byte ^= (row & 7) << 4;
        *reinterpret_cast<u16*>(Pw + byte) = f2bf(s[kt][r]);
      }
#pragma unroll
    for (int ks = 0; ks < 4; ++ks) {
      int pbyte = (lc << 8) + ks * 64 + lg * 16;
      pbyte ^= (lc & 7) << 4;
      bf16x8 pa = *reinterpret_cast<const bf16x8*>(Pw + pbyte);
#pragma unroll
      for (int ni = 0; ni < 4; ++ni) {
        const int vbyte = (ni * 16 + lc) * 256 + (((ks * 4 + lg) ^ (lc & 7)) << 4);
        bf16x8 bv = *reinterpret_cast<const bf16x8*>((const char*)Vs + vbyte);
        oa[ni] = __builtin_amdgcn_mfma_f32_16x16x32_bf16(pa, bv, oa[ni], 0, 0, 0);
      }
    }
  }

  float inv[4];
#pragma unroll
  for (int r = 0; r < 4; ++r) inv[r] = 1.0f / lsum[r];
#pragma unroll
  for (int ni = 0; ni < 4; ++ni)
#pragma unroll
    for (int r = 0; r < 4; ++r) {
      const int i = b * 512 + q0 + w * 16 + lg * 4 + r;
      const int j = h * 64 + ni * 16 + lc;
      o[((size_t)(j >> 5) * 16384 + i) * 32 + (j & 31)] = f2bf(oa[ni][r] * inv[r]);
    }
}

// ---------- launch ----------
extern "C" void kernel_launch(void* const* d_in, const int* in_sizes, int n_in,
                              void* d_out, int out_size, void* d_ws, size_t ws_size,
                              hipStream_t stream) {
  const float* x     = (const float*)d_in[0];
  const float* ebias = (const float*)d_in[1];
  const float* ln1g  = (const float*)d_in[2];
  const float* ln1b  = (const float*)d_in[3];
  const float* qkvw  = (const float*)d_in[4];
  const float* qkvb  = (const float*)d_in[5];
  const float* projw = (const float*)d_in[6];
  const float* projb = (const float*)d_in[7];
  const float* ln2g  = (const float*)d_in[8];
  const float* ln2b  = (const float*)d_in[9];
  const float* fc1w  = (const float*)d_in[10];
  const float* fc1b  = (const float*)d_in[11];
  const float* fc2w  = (const float*)d_in[12];
  const float* fc2b  = (const float*)d_in[13];
  float* out = (float*)d_out;

  char* p = (char*)d_ws;
  const size_t ACT = (size_t)16384 * 768 * 2;  // 25165824 B
  u16* xnb = (u16*)(p);                        // xn packed; later attn-out packed
  u16* qb  = (u16*)(p + ACT);
  u16* kb  = (u16*)(p + 2 * ACT);              // k; later ln2-out packed
  u16* vb  = (u16*)(p + 3 * ACT);              // V^T [bh][d][tok]
  u16* ffb = (u16*)(p + 4 * ACT);              // fc1 out packed; ebb shares (time-disjoint)
  u16* ebb = (u16*)(p + 4 * ACT);              // bf16 edge bias
  float* x2 = (float*)(p + 4 * ACT + (size_t)16384 * 3072 * 2);
  char* wz = p + 4 * ACT + (size_t)16384 * 3072 * 2 + (size_t)16384 * 768 * 4;
  u16* wq  = (u16*)wz;
  u16* wp  = wq + (size_t)2304 * 768;
  u16* wf1 = wp + (size_t)768 * 768;
  u16* wf2 = wf1 + (size_t)3072 * 768;

  cvt_all<<<6528, 256, 0, stream>>>(qkvw, projw, fc1w, fc2w, ebias,
                                    wq, wp, wf1, wf2, ebb);

  ln_bf16<<<16384, 192, 0, stream>>>(x, ln1g, ln1b, xnb);

  gemm_bt<EPI_QKV><<<dim3(9, 64), 512, 0, stream>>>(
      xnb, wq, qkvb, nullptr, nullptr, nullptr, qb, kb, vb, 16384, 2304, 768);

  attn_fwd<<<3072, 256, 0, stream>>>(qb, kb, vb, ebb, xnb);

  gemm_bt<EPI_PROJ><<<dim3(3, 64), 512, 0, stream>>>(
      xnb, wp, projb, x, x2, nullptr, nullptr, nullptr, nullptr, 16384, 768, 768);

  ln_bf16<<<16384, 192, 0, stream>>>(x2, ln2g, ln2b, kb);

  gemm_bt<EPI_GELU><<<dim3(12, 64), 512, 0, stream>>>(
      kb, wf1, fc1b, nullptr, nullptr, ffb, nullptr, nullptr, nullptr, 16384, 3072, 768);

  gemm_bt<EPI_OUT><<<dim3(3, 64), 512, 0, stream>>>(
      ffb, wf2, fc2b, x2, out, nullptr, nullptr, nullptr, nullptr, 16384, 768, 3072);
}